// Round 5
// baseline (510.815 us; speedup 1.0000x reference)
//
#include <hip/hip_runtime.h>

typedef unsigned int u32;
typedef unsigned short u16;
typedef __attribute__((ext_vector_type(4))) float f32x4;
typedef __attribute__((ext_vector_type(4))) int i32x4;
typedef __attribute__((ext_vector_type(2))) int i32x2;
typedef __attribute__((ext_vector_type(8))) short s16x8;

#define N_NODES 8192
#define F_DIM 512

#define BARRIER_NOVM() asm volatile("s_waitcnt lgkmcnt(0)\ns_barrier" ::: "memory")
#define WAITVM(n) asm volatile("s_waitcnt vmcnt(" #n ")" ::: "memory")

__device__ __forceinline__ int fm_swz(int m) {
    return ((m >> 2) & 7) ^ ((m & 3) << 1);
}

__device__ __forceinline__ u16 f2bf(float x) {
    u32 u = __builtin_bit_cast(u32, x);
    u = (u + 0x7FFFu + ((u >> 16) & 1u)) >> 16;
    return (u16)u;
}

__device__ __forceinline__ void glds16(const u16* g, u16* l) {
    __builtin_amdgcn_global_load_lds((const __attribute__((address_space(1))) u32*)g,
                                     (__attribute__((address_space(3))) u32*)l, 16, 0, 0);
}

// ---------------- Kernel 1: Yt[f][i] = bf16( sum_c W[c][f] * X[i][c] ); also zeroes deg ----------------
__global__ __launch_bounds__(256, 1)
void k1_xw(const float* __restrict__ X, const float* __restrict__ W, u16* __restrict__ Yt,
           int* __restrict__ deg) {
    __shared__ __align__(16) u16 Wl[128 * 64];
    __shared__ __align__(16) u16 Xl[128 * 64];

    const int tid = threadIdx.x;
    if (blockIdx.x < 8) {  // zero deg[8192] before k0's atomics (next kernel in stream)
        i32x4 z = {0, 0, 0, 0};
        *(i32x4*)(deg + blockIdx.x * 1024 + tid * 4) = z;
    }

    const int lane = tid & 63;
    const int wave = tid >> 6;
    const int wm = wave >> 1, wn = wave & 1;
    const int col = lane & 15, quad = lane >> 4;

    const int f0 = (blockIdx.x & 3) * 128;
    const int i0 = (blockIdx.x >> 2) * 128;

    const int cgrp = tid & 31;
    const int kk   = tid >> 5;
    const int xcq  = tid & 15;
    const int xig  = tid >> 4;

    f32x4 wr[8], xr[8];
    {
        const float* wp = W + (size_t)(kk * 8) * F_DIM + f0 + cgrp * 4;
        const float* xp = X + (size_t)(i0 + xig * 8) * F_DIM + xcq * 4;
#pragma unroll
        for (int r = 0; r < 8; ++r) wr[r] = *(const f32x4*)(wp + (size_t)r * F_DIM);
#pragma unroll
        for (int r = 0; r < 8; ++r) xr[r] = *(const f32x4*)(xp + (size_t)r * F_DIM);
    }

    f32x4 acc[4][4] = {};

    for (int s = 0; s < 8; ++s) {
        BARRIER_NOVM();
#pragma unroll
        for (int mm = 0; mm < 4; ++mm) {
            int m = cgrp * 4 + mm;
            u32 q0 = ((u32)f2bf(wr[1][mm]) << 16) | f2bf(wr[0][mm]);
            u32 q1 = ((u32)f2bf(wr[3][mm]) << 16) | f2bf(wr[2][mm]);
            u32 q2 = ((u32)f2bf(wr[5][mm]) << 16) | f2bf(wr[4][mm]);
            u32 q3 = ((u32)f2bf(wr[7][mm]) << 16) | f2bf(wr[6][mm]);
            i32x4 v = {(int)q0, (int)q1, (int)q2, (int)q3};
            *(i32x4*)&Wl[m * 64 + ((kk ^ fm_swz(m)) << 3)] = v;
        }
#pragma unroll
        for (int r = 0; r < 8; ++r) {
            int row = xig * 8 + r;
            u32 a = ((u32)f2bf(xr[r][1]) << 16) | f2bf(xr[r][0]);
            u32 b = ((u32)f2bf(xr[r][3]) << 16) | f2bf(xr[r][2]);
            int kc = xcq >> 1, half = xcq & 1;
            i32x2 v = {(int)a, (int)b};
            *(i32x2*)&Xl[row * 64 + ((kc ^ (row & 7)) << 3) + half * 4] = v;
        }
        BARRIER_NOVM();
        if (s + 1 < 8) {
            int c0 = (s + 1) * 64;
            const float* wp = W + (size_t)(c0 + kk * 8) * F_DIM + f0 + cgrp * 4;
            const float* xp = X + (size_t)(i0 + xig * 8) * F_DIM + c0 + xcq * 4;
#pragma unroll
            for (int r = 0; r < 8; ++r) wr[r] = *(const f32x4*)(wp + (size_t)r * F_DIM);
#pragma unroll
            for (int r = 0; r < 8; ++r) xr[r] = *(const f32x4*)(xp + (size_t)r * F_DIM);
        }
#pragma unroll
        for (int s2 = 0; s2 < 2; ++s2) {
            s16x8 af[4], bfr[4];
#pragma unroll
            for (int mi = 0; mi < 4; ++mi) {
                int m = wm * 64 + mi * 16 + col;
                int kc = s2 * 4 + quad;
                af[mi] = *(const s16x8*)&Wl[m * 64 + ((kc ^ fm_swz(m)) << 3)];
            }
#pragma unroll
            for (int ni = 0; ni < 4; ++ni) {
                int rr = wn * 64 + ni * 16 + col;
                int kc = s2 * 4 + quad;
                bfr[ni] = *(const s16x8*)&Xl[rr * 64 + ((kc ^ (rr & 7)) << 3)];
            }
#pragma unroll
            for (int mi = 0; mi < 4; ++mi)
#pragma unroll
                for (int ni = 0; ni < 4; ++ni)
                    acc[mi][ni] = __builtin_amdgcn_mfma_f32_16x16x32_bf16(af[mi], bfr[ni],
                                                                          acc[mi][ni], 0, 0, 0);
        }
    }

#pragma unroll
    for (int mi = 0; mi < 4; ++mi)
#pragma unroll
        for (int r = 0; r < 4; ++r) {
            int f = f0 + wm * 64 + mi * 16 + quad * 4 + r;
#pragma unroll
            for (int ni = 0; ni < 4; ++ni) {
                int i = i0 + wn * 64 + ni * 16 + col;
                Yt[(size_t)f * N_NODES + i] = f2bf(acc[mi][ni][r]);
            }
        }
}

// ---------------- Kernel 0: At[j][i] = bf16(adj[i][j]); deg[j] += column sums ----------------
// 128x128 tile; LDS layout [row j][16 slots of 16B], physical slot = logical ^ (row&7).
__global__ __launch_bounds__(256)
void k0_t(const int* __restrict__ adj, u16* __restrict__ At, int* __restrict__ deg) {
    __shared__ __align__(16) u16 T[128 * 128];  // 32 KB
    __shared__ int Dred[4][128];

    const int tid = threadIdx.x;
    const int i0 = (blockIdx.x & 63) * 128;
    const int j0 = (blockIdx.x >> 6) * 128;
    const int jj = (tid & 63) * 2;  // two consecutive j rows
    const int ih = tid >> 6;        // i-chunk of 32

    u32 pk[2][16];
    int d0 = 0, d1 = 0;
    const int* ap = adj + (size_t)(i0 + ih * 32) * N_NODES + j0 + jj;
#pragma unroll
    for (int r = 0; r < 32; ++r) {
        i32x2 v = *(const i32x2*)ap;
        ap += N_NODES;
        d0 += v[0]; d1 += v[1];
        u32 b0 = (u32)v[0] * 0x3F80u;
        u32 b1 = (u32)v[1] * 0x3F80u;
        if ((r & 1) == 0) { pk[0][r >> 1] = b0;        pk[1][r >> 1] = b1; }
        else              { pk[0][r >> 1] |= b0 << 16; pk[1][r >> 1] |= b1 << 16; }
    }
#pragma unroll
    for (int p = 0; p < 2; ++p) {
        int row = jj + p;
#pragma unroll
        for (int c = 0; c < 4; ++c) {
            int slot = (ih * 4 + c) ^ (row & 7);  // XOR<8 keeps bit3 -> same i-half
            i32x4 w = {(int)pk[p][c * 4], (int)pk[p][c * 4 + 1],
                       (int)pk[p][c * 4 + 2], (int)pk[p][c * 4 + 3]};
            *(i32x4*)&T[row * 128 + slot * 8] = w;
        }
    }
    Dred[ih][jj] = d0;
    Dred[ih][jj + 1] = d1;
    __syncthreads();

#pragma unroll
    for (int rep = 0; rep < 8; ++rep) {
        int row = (tid >> 4) + rep * 16;
        int slot = tid & 15;
        int ps = slot ^ (row & 7);
        i32x4 w = *(const i32x4*)&T[row * 128 + ps * 8];
        *(i32x4*)(At + (size_t)(j0 + row) * N_NODES + i0 + slot * 8) = w;
    }
    if (tid < 128) {
        int d = Dred[0][tid] + Dred[1][tid] + Dred[2][tid] + Dred[3][tid];
        atomicAdd(&deg[j0 + tid], d);
    }
}

// ---------------- Kernel 2: pure bf16 GEMM (m97 clone): part[kq][j][f] = sum adjT*Yt ----------------
// 128x128 tile, BK=64, single-buffered 32 KB LDS, 2-barrier K-loop, K-split 4 -> 4 blocks/CU.
__global__ __launch_bounds__(256, 4)
void k2_gemm(const u16* __restrict__ At, const u16* __restrict__ Yt,
             float* __restrict__ parts) {
    __shared__ __align__(16) u16 As[128 * 64];
    __shared__ __align__(16) u16 Bs[128 * 64];

    const int tid = threadIdx.x, lane = tid & 63, wave = tid >> 6;
    const int wm = wave >> 1, wn = wave & 1;
    const int col = lane & 15, quad = lane >> 4;

    // bid = f_idx*256 + kq*64 + stripe: 4 f-blocks of a (kq,stripe) share bid%8 (XCD L2)
    const int f_idx = blockIdx.x >> 8;
    const int kq = (blockIdx.x >> 6) & 3;
    const int stripe = blockIdx.x & 63;
    const int j0 = stripe * 128, f0 = f_idx * 128, ibase = kq * 2048;
    float* __restrict__ part = parts + (size_t)kq * N_NODES * F_DIM;

    const int rowl = lane >> 3;
    const int kc = (lane & 7) ^ rowl;

    f32x4 acc[4][4] = {};

    for (int s = 0; s < 32; ++s) {
        const int ik = ibase + s * 64;
#pragma unroll
        for (int gg = 0; gg < 4; ++gg) {
            const int g = wave * 4 + gg;
            glds16(At + (size_t)(j0 + g * 8 + rowl) * N_NODES + ik + kc * 8, &As[g * 512]);
            glds16(Yt + (size_t)(f0 + g * 8 + rowl) * N_NODES + ik + kc * 8, &Bs[g * 512]);
        }
        __syncthreads();  // drains vmcnt -> LDS tiles ready
#pragma unroll
        for (int s2 = 0; s2 < 2; ++s2) {
            s16x8 af[4], bfr[4];
#pragma unroll
            for (int mi = 0; mi < 4; ++mi) {
                int m = wm * 64 + mi * 16 + col;
                int k2i = s2 * 4 + quad;
                af[mi] = *(const s16x8*)&As[m * 64 + ((k2i ^ (m & 7)) << 3)];
            }
#pragma unroll
            for (int ni = 0; ni < 4; ++ni) {
                int rr = wn * 64 + ni * 16 + col;
                int k2i = s2 * 4 + quad;
                bfr[ni] = *(const s16x8*)&Bs[rr * 64 + ((k2i ^ (rr & 7)) << 3)];
            }
#pragma unroll
            for (int mi = 0; mi < 4; ++mi)
#pragma unroll
                for (int ni = 0; ni < 4; ++ni)
                    acc[mi][ni] = __builtin_amdgcn_mfma_f32_16x16x32_bf16(af[mi], bfr[ni],
                                                                          acc[mi][ni], 0, 0, 0);
        }
        __syncthreads();  // all waves done reading before restage
    }

#pragma unroll
    for (int mi = 0; mi < 4; ++mi)
#pragma unroll
        for (int r = 0; r < 4; ++r) {
            int jl = wm * 64 + mi * 16 + quad * 4 + r;
            size_t ob = (size_t)(j0 + jl) * F_DIM + f0 + wn * 64;
#pragma unroll
            for (int ni = 0; ni < 4; ++ni)
                part[ob + ni * 16 + col] = acc[mi][ni][r];
        }
}

// ---------------- Kernel 3: out = relu( rsqrt(max(deg,1)) * (p0+p1+p2+p3) ) ----------------
__global__ __launch_bounds__(256, 4)
void k3_4(const float* __restrict__ parts, const int* __restrict__ deg,
          float* __restrict__ out) {
    int idx = blockIdx.x * 256 + threadIdx.x;
    int j = idx >> 7;
    int c = (idx & 127) * 4;
    size_t off = (size_t)j * F_DIM + c;
    const size_t PS = (size_t)N_NODES * F_DIM;
    f32x4 a = *(const f32x4*)(parts + off);
    f32x4 b = *(const f32x4*)(parts + PS + off);
    f32x4 cc = *(const f32x4*)(parts + 2 * PS + off);
    f32x4 d = *(const f32x4*)(parts + 3 * PS + off);
    float nv = rsqrtf(fmaxf((float)deg[j], 1.0f));
    f32x4 v;
#pragma unroll
    for (int t = 0; t < 4; ++t) v[t] = fmaxf((a[t] + b[t] + cc[t] + d[t]) * nv, 0.0f);
    *(f32x4*)(out + off) = v;
}

// ================= Fallback path (R4) if workspace too small =================
__global__ __launch_bounds__(256, 2)
void k2_agg(const int* __restrict__ adj, const u16* __restrict__ Yt,
            float* __restrict__ p0, float* __restrict__ p1, int* __restrict__ degp) {
    __shared__ __align__(16) u16 Ab[2][128 * 64];
    __shared__ __align__(16) u16 Bb[3][128 * 64];

    const int tid = threadIdx.x;
    const int lane = tid & 63;
    const int wave = tid >> 6;
    const int wm = wave >> 1, wn = wave & 1;
    const int col = lane & 15, quad = lane >> 4;

    const int f_idx = blockIdx.x >> 7;
    const int unit = blockIdx.x & 127;
    const int khalf = unit >> 6;
    const int stripe = unit & 63;
    const int j0 = stripe * 128;
    const int f0 = f_idx * 128;
    const int ibase = khalf * 4096;
    float* __restrict__ part = khalf ? p1 : p0;

    const int cgrp = tid & 31;
    const int kk = tid >> 5;

    u32 dacc[4] = {0, 0, 0, 0};
    i32x4 avA[8], avB[8];

    const int rowl = lane >> 3;
    const int kcB = (lane & 7) ^ rowl;

    auto loadA = [&](int i0k, i32x4 (&av)[8]) {
        const int* ap = adj + (size_t)(i0k + kk * 8) * N_NODES + j0 + cgrp * 4;
#pragma unroll
        for (int r = 0; r < 8; ++r) av[r] = *(const i32x4*)(ap + (size_t)r * N_NODES);
    };
    auto stageB = [&](int i0k, int buf) {
#pragma unroll
        for (int gg = 0; gg < 4; ++gg) {
            int g = wave * 4 + gg;
            const u16* src = Yt + (size_t)(f0 + g * 8 + rowl) * N_NODES + i0k + kcB * 8;
            glds16(src, &Bb[buf][g * 512]);
        }
    };
    auto writeA = [&](const i32x4 (&av)[8], int buf) {
#pragma unroll
        for (int mm = 0; mm < 4; ++mm) {
            int m = cgrp * 4 + mm;
            u32 q0 = (u32)av[0][mm] | ((u32)av[1][mm] << 16);
            u32 q1 = (u32)av[2][mm] | ((u32)av[3][mm] << 16);
            u32 q2 = (u32)av[4][mm] | ((u32)av[5][mm] << 16);
            u32 q3 = (u32)av[6][mm] | ((u32)av[7][mm] << 16);
            dacc[mm] += q0 + q1 + q2 + q3;
            i32x4 v = {(int)(q0 * 0x3F80u), (int)(q1 * 0x3F80u),
                       (int)(q2 * 0x3F80u), (int)(q3 * 0x3F80u)};
            *(i32x4*)&Ab[buf][m * 64 + ((kk ^ fm_swz(m)) << 3)] = v;
        }
    };

    f32x4 acc[4][4] = {};

    loadA(ibase, avA);
    stageB(ibase, 0);
    loadA(ibase + 64, avB);
    stageB(ibase + 64, 1);
    writeA(avA, 0);
    WAITVM(12);
    BARRIER_NOVM();

    for (int s = 0; s < 64; ++s) {
        if (s + 2 < 64) {
            if (s & 1) loadA(ibase + (s + 2) * 64, avB);
            else       loadA(ibase + (s + 2) * 64, avA);
            stageB(ibase + (s + 2) * 64, (s + 2) % 3);
        }
        const u16* A = Ab[s & 1];
        const u16* B = Bb[s % 3];
#pragma unroll
        for (int s2 = 0; s2 < 2; ++s2) {
            s16x8 af[4], bfr[4];
#pragma unroll
            for (int mi = 0; mi < 4; ++mi) {
                int m = wm * 64 + mi * 16 + col;
                int kc = s2 * 4 + quad;
                af[mi] = *(const s16x8*)&A[m * 64 + ((kc ^ fm_swz(m)) << 3)];
            }
#pragma unroll
            for (int ni = 0; ni < 4; ++ni) {
                int rr = wn * 64 + ni * 16 + col;
                int kc = s2 * 4 + quad;
                bfr[ni] = *(const s16x8*)&B[rr * 64 + ((kc ^ (rr & 7)) << 3)];
            }
#pragma unroll
            for (int mi = 0; mi < 4; ++mi)
#pragma unroll
                for (int ni = 0; ni < 4; ++ni)
                    acc[mi][ni] = __builtin_amdgcn_mfma_f32_16x16x32_bf16(af[mi], bfr[ni],
                                                                          acc[mi][ni], 0, 0, 0);
        }
        if (s + 1 < 64) {
            if (s & 1) writeA(avA, (s + 1) & 1);
            else       writeA(avB, (s + 1) & 1);
        }
        if (s + 2 < 64) { WAITVM(12); }
        else            { WAITVM(0); }
        BARRIER_NOVM();
    }

    int* degs = (int*)&Ab[0][0];
    if (tid < 128) degs[tid] = 0;
    __syncthreads();
#pragma unroll
    for (int mm = 0; mm < 4; ++mm) {
        int d = (int)((dacc[mm] & 0xFFFFu) + (dacc[mm] >> 16));
        atomicAdd(&degs[cgrp * 4 + mm], d);
    }
    __syncthreads();
    if (f_idx == 0 && tid < 128) degp[khalf * N_NODES + j0 + tid] = degs[tid];

#pragma unroll
    for (int mi = 0; mi < 4; ++mi)
#pragma unroll
        for (int r = 0; r < 4; ++r) {
            int jl = wm * 64 + mi * 16 + quad * 4 + r;
            size_t ob = (size_t)(j0 + jl) * F_DIM + f0 + wn * 64;
#pragma unroll
            for (int ni = 0; ni < 4; ++ni)
                part[ob + ni * 16 + col] = acc[mi][ni][r];
        }
}

__global__ __launch_bounds__(256, 4)
void k3_combine(const float* __restrict__ p0, const float* __restrict__ p1,
                const int* __restrict__ degp, float* __restrict__ out) {
    int idx = blockIdx.x * 256 + threadIdx.x;
    int j = idx >> 7;
    int c = (idx & 127) * 4;
    size_t off = (size_t)j * F_DIM + c;
    f32x4 a = *(const f32x4*)(p0 + off);
    f32x4 b = *(const f32x4*)(p1 + off);
    int d = degp[j] + degp[N_NODES + j];
    float nv = rsqrtf(fmaxf((float)d, 1.0f));
    f32x4 v;
#pragma unroll
    for (int t = 0; t < 4; ++t) v[t] = fmaxf((a[t] + b[t]) * nv, 0.0f);
    *(f32x4*)(out + off) = v;
}

extern "C" void kernel_launch(void* const* d_in, const int* in_sizes, int n_in,
                              void* d_out, int out_size, void* d_ws, size_t ws_size,
                              hipStream_t stream) {
    (void)in_sizes; (void)n_in; (void)out_size;
    const float* X = (const float*)d_in[0];
    const int* adj = (const int*)d_in[1];
    const float* W = (const float*)d_in[2];
    float* out = (float*)d_out;
    char* w = (char*)d_ws;

    const size_t NEED = ((size_t)200 << 20) + 32768;
    if (ws_size >= NEED) {
        // ws: At 128Mi | Yt 8Mi | parts 64Mi | deg 32K
        u16* At = (u16*)w;
        u16* Yt = (u16*)(w + ((size_t)128 << 20));
        float* parts = (float*)(w + ((size_t)136 << 20));
        int* deg = (int*)(w + ((size_t)200 << 20));

        k1_xw<<<dim3(256), dim3(256), 0, stream>>>(X, W, Yt, deg);   // also zeroes deg
        k0_t<<<dim3(4096), dim3(256), 0, stream>>>(adj, At, deg);
        k2_gemm<<<dim3(1024), dim3(256), 0, stream>>>(At, Yt, parts);
        k3_4<<<dim3(4096), dim3(256), 0, stream>>>(parts, deg, out);
    } else {
        // fallback (R4 path): Yt 8Mi | p0 16Mi | p1 16Mi | degp 64K
        u16* Yt = (u16*)w;
        float* p0 = (float*)(w + (8u << 20));
        float* p1 = p0 + (size_t)N_NODES * F_DIM;
        int* degp = (int*)(w + (8u << 20) + (size_t)2 * N_NODES * F_DIM * 4);

        k1_xw<<<dim3(256), dim3(256), 0, stream>>>(X, W, Yt, degp);
        k2_agg<<<dim3(512), dim3(256), 0, stream>>>(adj, Yt, p0, p1, degp);
        k3_combine<<<dim3(4096), dim3(256), 0, stream>>>(p0, p1, degp, out);
    }
}